// Round 1
// baseline (149.125 us; speedup 1.0000x reference)
//
#include <hip/hip_runtime.h>

// BSpline evaluation, MI355X.
// Inputs: t [2048] f32 (sorted, t[-1]=32768), c [512,2048] f32, delta [1] i32.
// Output: sample_points [S] ++ spline_values [S, DIM], S = out_size/(1+DIM).
// Key fact: the reference's B matrix rows have <=4 nonzeros (cols j-3..j where
// j = knot span), including the "stale column" quirk (col i final degree =
// min(3, NK-1-i)). So we never materialize B.

#define DEG 3

// padded knot accessor: padded_t = [0,0,0,0, t...], length NK+4
__device__ __forceinline__ float kn(const float* __restrict__ t, int i) {
    return (i < DEG + 1) ? 0.0f : t[i - (DEG + 1)];
}

// ---------------- transpose c [DIM][NK] -> cT [NK][DIM] ----------------
#define TILE 32
__global__ __launch_bounds__(256) void transpose_kernel(
    const float* __restrict__ src, float* __restrict__ dst,
    int rows, int cols)  // src[rows][cols], dst[cols][rows]
{
    __shared__ float tile[TILE][TILE + 1];
    int x = blockIdx.x * TILE + threadIdx.x;            // col in src
    int y = blockIdx.y * TILE + threadIdx.y;            // row in src
    #pragma unroll
    for (int i = 0; i < TILE; i += 8) {
        if (y + i < rows && x < cols)
            tile[threadIdx.y + i][threadIdx.x] = src[(size_t)(y + i) * cols + x];
    }
    __syncthreads();
    int x2 = blockIdx.y * TILE + threadIdx.x;           // col in dst (= src row)
    int y2 = blockIdx.x * TILE + threadIdx.y;           // row in dst (= src col)
    #pragma unroll
    for (int i = 0; i < TILE; i += 8) {
        if (y2 + i < cols && x2 < rows)
            dst[(size_t)(y2 + i) * rows + x2] = tile[threadIdx.x][threadIdx.y + i];
    }
}

// ---------------- main eval: one block per sample ----------------
__global__ __launch_bounds__(128) void bspline_eval(
    const float* __restrict__ t, const int* __restrict__ delta_p,
    const float* __restrict__ cT, float* __restrict__ out,
    int S, int DIM, int NK)
{
    const int s = blockIdx.x;
    const float delta = (float)(*delta_p);
    const float sv = (float)s * delta;

    float* __restrict__ out_pts = out;
    float* __restrict__ out_spline = out + S;
    if (threadIdx.x == 0) out_pts[s] = sv;

    // rightmost j in [DEG, NK+DEG-1] with kn(j) <= sv  (kn(DEG)=0 <= sv always)
    int lo = DEG, hi = NK + DEG - 1;
    while (lo < hi) {
        int mid = (lo + hi + 1) >> 1;
        if (kn(t, mid) <= sv) lo = mid; else hi = mid - 1;
    }
    const int j = lo;

    const int nvec = DIM >> 2;  // DIM divisible by 4 (512)
    float4* __restrict__ orow = (float4*)(out_spline + (size_t)s * DIM);

    if (j >= NK) {
        // sample beyond last degree-0 span: B row is identically zero.
        for (int d = (int)threadIdx.x; d < nvec; d += blockDim.x)
            orow[d] = make_float4(0.f, 0.f, 0.f, 0.f);
        return;
    }

    // Cox-de Boor triangle: N[d][k] = val(j-d+k, d), with where(denom==0 -> 0)
    float N[DEG + 1][DEG + 1];
    N[0][0] = 1.0f;
    #pragma unroll
    for (int d = 1; d <= DEG; ++d) {
        #pragma unroll
        for (int k = 0; k <= d; ++k) {
            int i = j - d + k;
            float vpi  = (k >= 1) ? N[d - 1][k - 1] : 0.0f;  // val(i,   d-1)
            float vpi1 = (k <= d - 1) ? N[d - 1][k] : 0.0f;  // val(i+1, d-1)
            float ki   = kn(t, i);
            float kid  = kn(t, i + d);
            float ki1  = kn(t, i + 1);
            float kid1 = kn(t, i + d + 1);
            float den1 = kid - ki;
            float den2 = kid1 - ki1;
            float w1 = (den1 != 0.0f) ? (sv - ki) / den1 : 0.0f;
            float w2 = (den2 != 0.0f) ? (kid1 - sv) / den2 : 0.0f;
            N[d][k] = w1 * vpi + w2 * vpi1;
        }
    }

    // final column values: col i keeps degree min(DEG, NK-1-i) (stale-col quirk)
    float b[DEG + 1];
    #pragma unroll
    for (int m = 0; m <= DEG; ++m) {
        int col = j - DEG + m;
        int deg = NK - 1 - col; if (deg > DEG) deg = DEG;
        int idx = m - DEG + deg;             // col - (j - deg)
        b[m] = (idx >= 0) ? N[deg][idx] : 0.0f;
    }

    const float4* __restrict__ r0 = (const float4*)(cT + (size_t)(j - 3) * DIM);
    const float4* __restrict__ r1 = (const float4*)(cT + (size_t)(j - 2) * DIM);
    const float4* __restrict__ r2 = (const float4*)(cT + (size_t)(j - 1) * DIM);
    const float4* __restrict__ r3 = (const float4*)(cT + (size_t)(j    ) * DIM);
    const float b0 = b[0], b1 = b[1], b2 = b[2], b3 = b[3];

    for (int d = (int)threadIdx.x; d < nvec; d += blockDim.x) {
        float4 a0 = r0[d], a1 = r1[d], a2 = r2[d], a3 = r3[d];
        float4 o;
        o.x = b0 * a0.x + b1 * a1.x + b2 * a2.x + b3 * a3.x;
        o.y = b0 * a0.y + b1 * a1.y + b2 * a2.y + b3 * a3.y;
        o.z = b0 * a0.z + b1 * a1.z + b2 * a2.z + b3 * a3.z;
        o.w = b0 * a0.w + b1 * a1.w + b2 * a2.w + b3 * a3.w;
        orow[d] = o;
    }
}

extern "C" void kernel_launch(void* const* d_in, const int* in_sizes, int n_in,
                              void* d_out, int out_size, void* d_ws, size_t ws_size,
                              hipStream_t stream) {
    const float* t = (const float*)d_in[0];
    const float* c = (const float*)d_in[1];
    const int* delta = (const int*)d_in[2];
    const int NK = in_sizes[0];                 // 2048
    const int DIM = in_sizes[1] / NK;           // 512
    const int S = out_size / (1 + DIM);         // 32768

    float* cT = (float*)d_ws;                   // NK*DIM floats = 4 MB

    dim3 tb(TILE, 8);
    dim3 tg((NK + TILE - 1) / TILE, (DIM + TILE - 1) / TILE);
    transpose_kernel<<<tg, tb, 0, stream>>>(c, cT, DIM, NK);

    bspline_eval<<<S, 128, 0, stream>>>(t, delta, cT, (float*)d_out, S, DIM, NK);
}

// Round 2
// 97.141 us; speedup vs baseline: 1.5351x; 1.5351x over previous
//
#include <hip/hip_runtime.h>

// BSpline evaluation, MI355X.
// t [2048] f32 sorted, c [512,2048] f32, delta [1] i32.
// out = sample_points [S] ++ spline_values [S, DIM]; S=32768, DIM=512.
// B rows have <=4 nonzeros (cols j-3..j, j = knot span), incl. the reference's
// stale-column quirk (col i final degree = min(3, NK-1-i)).
// Structure: transpose c -> cT; per-sample weights kernel (search+triangle,
// once per sample); streaming eval kernel (pure FMA, wave-uniform scalar b/j).

#define DEG 3

__device__ __forceinline__ float kn(const float* __restrict__ t, int i) {
    return (i < DEG + 1) ? 0.0f : t[i - (DEG + 1)];
}

// ---------------- transpose c [DIM][NK] -> cT [NK][DIM] ----------------
#define TILE 32
__global__ __launch_bounds__(256) void transpose_kernel(
    const float* __restrict__ src, float* __restrict__ dst,
    int rows, int cols)  // src[rows][cols], dst[cols][rows]
{
    __shared__ float tile[TILE][TILE + 1];
    int x = blockIdx.x * TILE + threadIdx.x;
    int y = blockIdx.y * TILE + threadIdx.y;
    #pragma unroll
    for (int i = 0; i < TILE; i += 8) {
        if (y + i < rows && x < cols)
            tile[threadIdx.y + i][threadIdx.x] = src[(size_t)(y + i) * cols + x];
    }
    __syncthreads();
    int x2 = blockIdx.y * TILE + threadIdx.x;
    int y2 = blockIdx.x * TILE + threadIdx.y;
    #pragma unroll
    for (int i = 0; i < TILE; i += 8) {
        if (y2 + i < cols && x2 < rows)
            dst[(size_t)(y2 + i) * rows + x2] = tile[threadIdx.x][threadIdx.y + i];
    }
}

// ---------------- weights: one thread per sample ----------------
__global__ __launch_bounds__(256) void weights_kernel(
    const float* __restrict__ t, const int* __restrict__ delta_p,
    float* __restrict__ out_pts, int* __restrict__ jbuf,
    float4* __restrict__ bbuf, int S, int NK)
{
    int s = blockIdx.x * blockDim.x + threadIdx.x;
    if (s >= S) return;
    const float delta = (float)(*delta_p);
    const float sv = (float)s * delta;
    out_pts[s] = sv;

    // rightmost j in [DEG, NK+DEG-1] with kn(j) <= sv
    int lo = DEG, hi = NK + DEG - 1;
    while (lo < hi) {
        int mid = (lo + hi + 1) >> 1;
        if (kn(t, mid) <= sv) lo = mid; else hi = mid - 1;
    }
    const int j = lo;

    if (j >= NK) {  // B row identically zero
        jbuf[s] = NK - 1;
        bbuf[s] = make_float4(0.f, 0.f, 0.f, 0.f);
        return;
    }

    // Cox-de Boor triangle: N[d][k] = val(j-d+k, d), where(denom==0 -> 0)
    float N[DEG + 1][DEG + 1];
    N[0][0] = 1.0f;
    #pragma unroll
    for (int d = 1; d <= DEG; ++d) {
        #pragma unroll
        for (int k = 0; k <= d; ++k) {
            int i = j - d + k;
            float vpi  = (k >= 1) ? N[d - 1][k - 1] : 0.0f;
            float vpi1 = (k <= d - 1) ? N[d - 1][k] : 0.0f;
            float ki   = kn(t, i);
            float kid  = kn(t, i + d);
            float ki1  = kn(t, i + 1);
            float kid1 = kn(t, i + d + 1);
            float den1 = kid - ki;
            float den2 = kid1 - ki1;
            float w1 = (den1 != 0.0f) ? (sv - ki) / den1 : 0.0f;
            float w2 = (den2 != 0.0f) ? (kid1 - sv) / den2 : 0.0f;
            N[d][k] = w1 * vpi + w2 * vpi1;
        }
    }

    // stale-column quirk: col i keeps degree min(DEG, NK-1-i)
    float b[DEG + 1];
    #pragma unroll
    for (int m = 0; m <= DEG; ++m) {
        int col = j - DEG + m;
        int deg = NK - 1 - col; if (deg > DEG) deg = DEG;
        int idx = m - DEG + deg;
        b[m] = (idx >= 0) ? N[deg][idx] : 0.0f;
    }
    jbuf[s] = j;
    bbuf[s] = make_float4(b[0], b[1], b[2], b[3]);
}

// ---------------- streaming eval: one thread per output float4 ----------------
// DIM=512 -> 128 float4 per sample; wave (64 lanes) covers half a sample row,
// so s is wave-uniform -> scalarize j/b loads.
__global__ __launch_bounds__(256) void bspline_eval(
    const int* __restrict__ jbuf, const float4* __restrict__ bbuf,
    const float* __restrict__ cT, float4* __restrict__ out_spline,
    int DIM)
{
    const int nvec = DIM >> 2;  // 128
    int g = blockIdx.x * blockDim.x + threadIdx.x;
    int s = __builtin_amdgcn_readfirstlane(g >> 7);  // wave-uniform sample id
    int d = g & (nvec - 1);

    const int j = jbuf[s];
    const float4 b = bbuf[s];

    const float4* __restrict__ r = (const float4*)(cT + (size_t)(j - 3) * DIM);
    float4 a0 = r[d];
    float4 a1 = r[d + nvec];
    float4 a2 = r[d + 2 * nvec];
    float4 a3 = r[d + 3 * nvec];

    float4 o;
    o.x = b.x * a0.x + b.y * a1.x + b.z * a2.x + b.w * a3.x;
    o.y = b.x * a0.y + b.y * a1.y + b.z * a2.y + b.w * a3.y;
    o.z = b.x * a0.z + b.y * a1.z + b.z * a2.z + b.w * a3.z;
    o.w = b.x * a0.w + b.y * a1.w + b.z * a2.w + b.w * a3.w;
    out_spline[(size_t)s * nvec + d] = o;
}

extern "C" void kernel_launch(void* const* d_in, const int* in_sizes, int n_in,
                              void* d_out, int out_size, void* d_ws, size_t ws_size,
                              hipStream_t stream) {
    const float* t = (const float*)d_in[0];
    const float* c = (const float*)d_in[1];
    const int* delta = (const int*)d_in[2];
    const int NK = in_sizes[0];                 // 2048
    const int DIM = in_sizes[1] / NK;           // 512
    const int S = out_size / (1 + DIM);         // 32768

    float* cT = (float*)d_ws;                               // NK*DIM f32 = 4 MB
    int* jbuf = (int*)((char*)d_ws + (size_t)NK * DIM * 4); // S ints
    float4* bbuf = (float4*)((char*)jbuf + (size_t)S * 4);  // S float4

    dim3 tb(TILE, 8);
    dim3 tg((NK + TILE - 1) / TILE, (DIM + TILE - 1) / TILE);
    transpose_kernel<<<tg, tb, 0, stream>>>(c, cT, DIM, NK);

    weights_kernel<<<(S + 255) / 256, 256, 0, stream>>>(
        t, delta, (float*)d_out, jbuf, bbuf, S, NK);

    int total = S * (DIM >> 2);                 // 4.19M threads
    bspline_eval<<<total / 256, 256, 0, stream>>>(
        jbuf, bbuf, cT, (float4*)((float*)d_out + S), DIM);
}

// Round 4
// 93.928 us; speedup vs baseline: 1.5876x; 1.0342x over previous
//
#include <hip/hip_runtime.h>

// BSpline evaluation, MI355X.
// t [2048] f32 sorted, c [512,2048] f32, delta [1] i32.
// out = sample_points [S] ++ spline_values [S, DIM]; S=32768, DIM=512.
// B rows have <=4 nonzeros (cols j-3..j, j = knot span), incl. the reference's
// stale-column quirk (col i final degree = min(3, NK-1-i)).
// R4: R3 with native-vector type for nontemporal stores (HIP float4 is a
// class type the builtin rejects).

#define DEG 3

typedef float vfloat4 __attribute__((ext_vector_type(4)));  // native vec for builtins

__device__ __forceinline__ float kn(const float* __restrict__ t, int i) {
    return (i < DEG + 1) ? 0.0f : t[i - (DEG + 1)];
}

// ---------------- fused prep: transpose c + per-sample weights ----------------
// blocks [0, TB): transpose c [DIM][NK] -> cT [NK][DIM], 32x32 tiles
// blocks [TB, TB+WB): weights (span search + Cox-de Boor triangle per sample)
#define TILE 32
__global__ __launch_bounds__(256) void prep_kernel(
    const float* __restrict__ c, float* __restrict__ cT,
    const float* __restrict__ t, const int* __restrict__ delta_p,
    float* __restrict__ out_pts, int* __restrict__ jbuf,
    vfloat4* __restrict__ bbuf, int S, int NK, int DIM, int TB)
{
    if ((int)blockIdx.x < TB) {
        __shared__ float tile[TILE][TILE + 1];
        int bx = blockIdx.x % (NK / TILE);
        int by = blockIdx.x / (NK / TILE);
        int tx = threadIdx.x % TILE;
        int ty = threadIdx.x / TILE;         // 0..7
        int x = bx * TILE + tx;
        int y = by * TILE + ty;
        #pragma unroll
        for (int i = 0; i < TILE; i += 8)
            tile[ty + i][tx] = c[(size_t)(y + i) * NK + x];
        __syncthreads();
        int x2 = by * TILE + tx;
        int y2 = bx * TILE + ty;
        #pragma unroll
        for (int i = 0; i < TILE; i += 8)
            cT[(size_t)(y2 + i) * DIM + x2] = tile[tx][ty + i];
        return;
    }

    // ---- weights part ----
    int s = (blockIdx.x - TB) * blockDim.x + threadIdx.x;
    if (s >= S) return;
    const float delta = (float)(*delta_p);
    const float sv = (float)s * delta;
    out_pts[s] = sv;

    // rightmost j in [DEG, NK+DEG-1] with kn(j) <= sv
    int lo = DEG, hi = NK + DEG - 1;
    while (lo < hi) {
        int mid = (lo + hi + 1) >> 1;
        if (kn(t, mid) <= sv) lo = mid; else hi = mid - 1;
    }
    const int j = lo;

    if (j >= NK) {  // beyond last degree-0 span: B row identically zero
        jbuf[s] = NK - 1;
        bbuf[s] = (vfloat4){0.f, 0.f, 0.f, 0.f};
        return;
    }

    // Cox-de Boor triangle: N[d][k] = val(j-d+k, d), where(denom==0 -> 0)
    float N[DEG + 1][DEG + 1];
    N[0][0] = 1.0f;
    #pragma unroll
    for (int d = 1; d <= DEG; ++d) {
        #pragma unroll
        for (int k = 0; k <= d; ++k) {
            int i = j - d + k;
            float vpi  = (k >= 1) ? N[d - 1][k - 1] : 0.0f;
            float vpi1 = (k <= d - 1) ? N[d - 1][k] : 0.0f;
            float ki   = kn(t, i);
            float kid  = kn(t, i + d);
            float ki1  = kn(t, i + 1);
            float kid1 = kn(t, i + d + 1);
            float den1 = kid - ki;
            float den2 = kid1 - ki1;
            float w1 = (den1 != 0.0f) ? (sv - ki) / den1 : 0.0f;
            float w2 = (den2 != 0.0f) ? (kid1 - sv) / den2 : 0.0f;
            N[d][k] = w1 * vpi + w2 * vpi1;
        }
    }

    // stale-column quirk: col i keeps degree min(DEG, NK-1-i)
    float b[DEG + 1];
    #pragma unroll
    for (int m = 0; m <= DEG; ++m) {
        int col = j - DEG + m;
        int deg = NK - 1 - col; if (deg > DEG) deg = DEG;
        int idx = m - DEG + deg;
        b[m] = (idx >= 0) ? N[deg][idx] : 0.0f;
    }
    jbuf[s] = j;
    bbuf[s] = (vfloat4){b[0], b[1], b[2], b[3]};
}

// ---------------- streaming eval: 4 consecutive samples per thread ----------
// Wave handles sample-group s0..s0+3 and 64 of 128 float4 lanes of the row;
// s0 and all four j's are wave-uniform -> uniform branch, scalarized loads.
// Fast path (j0==j3, ~78% of groups): one set of row loads -> 4 outputs.
__device__ __forceinline__ vfloat4 dot4(const vfloat4 b, const vfloat4 a0,
                                        const vfloat4 a1, const vfloat4 a2,
                                        const vfloat4 a3) {
    return b.x * a0 + b.y * a1 + b.z * a2 + b.w * a3;
}

__global__ __launch_bounds__(256) void bspline_eval(
    const int* __restrict__ jbuf, const vfloat4* __restrict__ bbuf,
    const float* __restrict__ cT, vfloat4* __restrict__ out_spline,
    int DIM)
{
    const int nvec = DIM >> 2;                    // 128
    int gtid = blockIdx.x * blockDim.x + threadIdx.x;
    int wid  = gtid >> 6;
    int lane = gtid & 63;
    int grp  = wid >> 1;                          // sample group (wave-uniform)
    int d    = ((wid & 1) << 6) | lane;           // 0..127
    int s0   = __builtin_amdgcn_readfirstlane(grp << 2);

    const int j0 = jbuf[s0 + 0];
    const int j3 = jbuf[s0 + 3];
    const vfloat4 b0 = bbuf[s0 + 0];
    const vfloat4 b1 = bbuf[s0 + 1];
    const vfloat4 b2 = bbuf[s0 + 2];
    const vfloat4 b3 = bbuf[s0 + 3];

    vfloat4* o = out_spline + (size_t)s0 * nvec + d;

    if (j0 == j3) {
        const vfloat4* r = (const vfloat4*)(cT + (size_t)(j3 - 3) * DIM) + d;
        vfloat4 a0 = r[0];
        vfloat4 a1 = r[nvec];
        vfloat4 a2 = r[2 * nvec];
        vfloat4 a3 = r[3 * nvec];
        __builtin_nontemporal_store(dot4(b0, a0, a1, a2, a3), o);
        __builtin_nontemporal_store(dot4(b1, a0, a1, a2, a3), o + nvec);
        __builtin_nontemporal_store(dot4(b2, a0, a1, a2, a3), o + 2 * nvec);
        __builtin_nontemporal_store(dot4(b3, a0, a1, a2, a3), o + 3 * nvec);
    } else {
        const int j1 = jbuf[s0 + 1];
        const int j2 = jbuf[s0 + 2];
        const int js[4] = {j0, j1, j2, j3};
        const vfloat4 bs[4] = {b0, b1, b2, b3};
        #pragma unroll
        for (int m = 0; m < 4; ++m) {
            const vfloat4* r = (const vfloat4*)(cT + (size_t)(js[m] - 3) * DIM) + d;
            vfloat4 a0 = r[0];
            vfloat4 a1 = r[nvec];
            vfloat4 a2 = r[2 * nvec];
            vfloat4 a3 = r[3 * nvec];
            __builtin_nontemporal_store(dot4(bs[m], a0, a1, a2, a3), o + m * nvec);
        }
    }
}

extern "C" void kernel_launch(void* const* d_in, const int* in_sizes, int n_in,
                              void* d_out, int out_size, void* d_ws, size_t ws_size,
                              hipStream_t stream) {
    const float* t = (const float*)d_in[0];
    const float* c = (const float*)d_in[1];
    const int* delta = (const int*)d_in[2];
    const int NK = in_sizes[0];                 // 2048
    const int DIM = in_sizes[1] / NK;           // 512
    const int S = out_size / (1 + DIM);         // 32768

    float* cT = (float*)d_ws;                                  // NK*DIM f32 = 4 MB
    int* jbuf = (int*)((char*)d_ws + (size_t)NK * DIM * 4);    // S ints
    vfloat4* bbuf = (vfloat4*)((char*)jbuf + (size_t)S * 4);   // S vfloat4

    const int TB = (NK / TILE) * (DIM / TILE);  // transpose blocks: 64*16=1024
    const int WB = (S + 255) / 256;             // weights blocks: 128
    prep_kernel<<<TB + WB, 256, 0, stream>>>(
        c, cT, t, delta, (float*)d_out, jbuf, bbuf, S, NK, DIM, TB);

    int total_threads = (S >> 2) * (DIM >> 2);  // 1.048M
    bspline_eval<<<total_threads / 256, 256, 0, stream>>>(
        jbuf, bbuf, cT, (vfloat4*)((float*)d_out + S), DIM);
}